// Round 9
// baseline (168.457 us; speedup 1.0000x reference)
//
#include <hip/hip_runtime.h>
#include <hip/hip_bf16.h>
#include <cstdint>

// Problem: B=32, T1=T2=512, D=128, gamma=1.0
// out[b] = softDTW( 1 - cos_sim(x[b], y[b]) )
//
// ws layout (floats):
//   invnx : 32*512            =     16,384
//   invny : 32*512            =     16,384
//   skew  : 32*1023*512       = 16,760,832   (cost/ln2 in anti-diagonal layout)

#define BT      32
#define TLEN    512
#define DF      128
#define NDIAG   1023          // kd = 0..1022  (kd = i-1 + j-1)
#define BIGV    1e30f
#define INV_LN2 1.44269504088896340f
#define LN2     0.69314718055994531f

// ------------------------------------------------------------- inverse norms
__global__ __launch_bounds__(256) void sdtw_invnorm(const float* __restrict__ x,
                                                    const float* __restrict__ y,
                                                    float* __restrict__ ox,
                                                    float* __restrict__ oy) {
    const float* in  = blockIdx.y ? y : x;
    float*       out = blockIdx.y ? oy : ox;
    int row = blockIdx.x * 4 + (threadIdx.x >> 6);
    int t   = threadIdx.x & 63;
    const float2* ip = reinterpret_cast<const float2*>(in + (size_t)row * DF);
    float2 v = ip[t];
    float s = v.x * v.x + v.y * v.y;
    #pragma unroll
    for (int o = 32; o; o >>= 1) s += __shfl_xor(s, o);
    if (t == 0) out[row] = 1.0f / fmaxf(sqrtf(s), 1e-12f);
}

// ------------------------------------------------- cosine-dist GEMM -> skew
#define KC   32
#define SPAD 132

__global__ __launch_bounds__(256) void sdtw_gemm_skew(const float* __restrict__ x,
                                                      const float* __restrict__ y,
                                                      const float* __restrict__ invnx,
                                                      const float* __restrict__ invny,
                                                      float* __restrict__ skew) {
    __shared__ float smem[16640];
    float* xs = smem;                        // [KC][SPAD] transposed: xs[k][row]
    float* ys = smem + KC * SPAD;

    const int b  = blockIdx.z;
    const int r0 = blockIdx.y * 128;
    const int c0 = blockIdx.x * 128;
    const int tid = threadIdx.x;
    const int tx = tid & 15, ty = tid >> 4;

    const float* xb = x + ((size_t)b * TLEN + r0) * DF;
    const float* yb = y + ((size_t)b * TLEN + c0) * DF;

    float acc[8][8];
    #pragma unroll
    for (int i = 0; i < 8; ++i)
        #pragma unroll
        for (int j = 0; j < 8; ++j) acc[i][j] = 0.0f;

    for (int kb = 0; kb < DF; kb += KC) {
        __syncthreads();
        #pragma unroll
        for (int i = 0; i < 4; ++i) {
            int g   = tid + i * 256;
            int row = g >> 3;
            int kq  = g & 7;
            float4 vx = *reinterpret_cast<const float4*>(xb + (size_t)row * DF + kb + kq * 4);
            float4 vy = *reinterpret_cast<const float4*>(yb + (size_t)row * DF + kb + kq * 4);
            xs[(kq * 4 + 0) * SPAD + row] = vx.x;
            xs[(kq * 4 + 1) * SPAD + row] = vx.y;
            xs[(kq * 4 + 2) * SPAD + row] = vx.z;
            xs[(kq * 4 + 3) * SPAD + row] = vx.w;
            ys[(kq * 4 + 0) * SPAD + row] = vy.x;
            ys[(kq * 4 + 1) * SPAD + row] = vy.y;
            ys[(kq * 4 + 2) * SPAD + row] = vy.z;
            ys[(kq * 4 + 3) * SPAD + row] = vy.w;
        }
        __syncthreads();
        #pragma unroll
        for (int k = 0; k < KC; ++k) {
            float ax[8], ay[8];
            *reinterpret_cast<float4*>(&ax[0]) = *reinterpret_cast<const float4*>(&xs[k * SPAD + ty * 8]);
            *reinterpret_cast<float4*>(&ax[4]) = *reinterpret_cast<const float4*>(&xs[k * SPAD + ty * 8 + 4]);
            *reinterpret_cast<float4*>(&ay[0]) = *reinterpret_cast<const float4*>(&ys[k * SPAD + tx * 8]);
            *reinterpret_cast<float4*>(&ay[4]) = *reinterpret_cast<const float4*>(&ys[k * SPAD + tx * 8 + 4]);
            #pragma unroll
            for (int i = 0; i < 8; ++i)
                #pragma unroll
                for (int j = 0; j < 8; ++j)
                    acc[i][j] = fmaf(ax[i], ay[j], acc[i][j]);
        }
    }

    // epilogue: (1 - dot*invnx*invny)/ln2 into LDS tile [128][130]
    float rn[8], cn[8];
    #pragma unroll
    for (int i = 0; i < 8; ++i) rn[i] = invnx[b * TLEN + r0 + ty * 8 + i];
    #pragma unroll
    for (int j = 0; j < 8; ++j) cn[j] = invny[b * TLEN + c0 + tx * 8 + j];

    __syncthreads();
    float* cs = smem;
    #pragma unroll
    for (int i = 0; i < 8; ++i)
        #pragma unroll
        for (int j = 0; j < 8; ++j)
            cs[(ty * 8 + i) * 130 + tx * 8 + j] =
                (1.0f - acc[i][j] * rn[i] * cn[j]) * INV_LN2;
    __syncthreads();

    float* sk = skew + (size_t)b * (NDIAG * TLEN);
    const int wv = tid >> 6, l = tid & 63;
    for (int dd = wv; dd < 255; dd += 4) {
        int lo = max(0, dd - 127), hi = min(127, dd);
        size_t base = (size_t)(r0 + c0 + dd) * TLEN + r0;
        for (int rb = lo; rb <= hi; rb += 64) {
            int rl = rb + l;
            if (rl <= hi) sk[base + rl] = cs[rl * 129 + dd];   // rl*130 + (dd-rl)
        }
    }
}

// ----------------------------------------------------------------- DTW DP
// 4 waves per batch (256 threads); lane owns TWO adjacent rows
// r0 = 128w + 2lt, r1 = r0+1. Wave w processes diag kd at phase p = kd+16w;
// one __syncthreads per 16-phase segment (stagger 16, consume-lag 17 ->
// every boundary quad is written a full segment before its hoisted read).
// Per phase: TWO INDEPENDENT softmin chains (cell r1 is fully lane-local:
// dg=PO0, left=PN1, up=PN0; cell r0 needs one DPP wave_shr:1 with old=bd_up
// for the lane-0 patch; dg0 = previous phase's patched up0, carried in dgs).
// The ILP-2 fills the dependency-chain stalls that bounded the 8-wave
// 1-cell version (43% per-CU VALUBusy -> waves stalled in lockstep).
// Segment modes per wave (wave-uniform): JUNK / PARTIAL(mask+clamp,
// sw in [-1,7]u[32,39], sw==-1 is warm-up that re-primes prefetch and
// rebuilds bd_up/dgs from real quads) / INTERIOR (sw in [8,31], no mask).
// 67 segments * 16 = 1072 phases; answer: diag 1022 (even -> Q) cell1 of
// lane 63 wave 3 = tid 255.

__device__ __forceinline__ int clampi(int v) {
    return v < 0 ? 0 : (v > NDIAG - 1 ? NDIAG - 1 : v);
}

__device__ __forceinline__ float dpp_shr1_old(float old, float x) {
    return __builtin_bit_cast(float,
        __builtin_amdgcn_update_dpp(__builtin_bit_cast(int, old),
                                    __builtin_bit_cast(int, x),
                                    0x138 /*wave_shr:1*/, 0xF, 0xF, false));
}

#define PH2(s, CC, PN0, PN1, PO0, PO1, NQC, MASKED, CLAMPED)                   \
  {                                                                            \
    float up0_ = dpp_shr1_old(bd_up, PN1);   /* lane0 <- bd_up */              \
    /* cell r1: dg=PO0 (pre-overwrite), left=PN1, up=PN0 -- lane-local */      \
    float m1_   = fminf(fminf(PO0, PN1), PN0);                                 \
    float mid1_ = __builtin_amdgcn_fmed3f(PO0, PN1, PN0);                      \
    float mx1_  = fmaxf(fmaxf(PO0, PN1), PN0);                                 \
    float e1_   = 1.0f + __builtin_amdgcn_exp2f(m1_ - mid1_)                   \
                       + __builtin_amdgcn_exp2f(m1_ - mx1_);                   \
    float v1_   = CC.y + m1_ - __builtin_amdgcn_logf(e1_);                     \
    /* cell r0: dg=dgs (prev patched up0), left=PN0, up=up0_ */                \
    float m0_   = fminf(fminf(dgs, PN0), up0_);                                \
    float mid0_ = __builtin_amdgcn_fmed3f(dgs, PN0, up0_);                     \
    float mx0_  = fmaxf(fmaxf(dgs, PN0), up0_);                                \
    float e0_   = 1.0f + __builtin_amdgcn_exp2f(m0_ - mid0_)                   \
                       + __builtin_amdgcn_exp2f(m0_ - mx0_);                   \
    float v0_   = CC.x + m0_ - __builtin_amdgcn_logf(e0_);                     \
    PO0 = (MASKED) ? (((unsigned)(vb0 + (s))     < 512u) ? v0_ : vBig) : v0_;  \
    PO1 = (MASKED) ? (((unsigned)(vb0 + (s) - 1) < 512u) ? v1_ : vBig) : v1_;  \
    if (((s) & 3) == 0) bq.x = PO1;                                            \
    if (((s) & 3) == 1) bq.y = PO1;                                            \
    if (((s) & 3) == 2) bq.z = PO1;                                            \
    if (((s) & 3) == 3) { bq.w = PO1;                                          \
      if (lt == 63) bnd4[w + 1][(q0 + ((s) >> 2)) & 7] = bq; }                 \
    bd_up = (NQC);                                                             \
    dgs = up0_;                                                                \
    { int kl_ = kd0 + (s) + 8; if (CLAMPED) kl_ = clampi(kl_);                 \
      CC = skb2[(size_t)kl_ * 256]; }                                          \
  }

#define SEG_BODY(MASKED, CLAMPED)                                              \
    PH2(0,  c0, P0, P1, Q0, Q1, nq0.x, MASKED, CLAMPED)                        \
    PH2(1,  c1, Q0, Q1, P0, P1, nq0.y, MASKED, CLAMPED)                        \
    PH2(2,  c2, P0, P1, Q0, Q1, nq0.z, MASKED, CLAMPED)                        \
    PH2(3,  c3, Q0, Q1, P0, P1, nq0.w, MASKED, CLAMPED)                        \
    PH2(4,  c4, P0, P1, Q0, Q1, nq1.x, MASKED, CLAMPED)                        \
    PH2(5,  c5, Q0, Q1, P0, P1, nq1.y, MASKED, CLAMPED)                        \
    PH2(6,  c6, P0, P1, Q0, Q1, nq1.z, MASKED, CLAMPED)                        \
    PH2(7,  c7, Q0, Q1, P0, P1, nq1.w, MASKED, CLAMPED)                        \
    PH2(8,  c0, P0, P1, Q0, Q1, nq2.x, MASKED, CLAMPED)                        \
    PH2(9,  c1, Q0, Q1, P0, P1, nq2.y, MASKED, CLAMPED)                        \
    PH2(10, c2, P0, P1, Q0, Q1, nq2.z, MASKED, CLAMPED)                        \
    PH2(11, c3, Q0, Q1, P0, P1, nq2.w, MASKED, CLAMPED)                        \
    PH2(12, c4, P0, P1, Q0, Q1, nq3.x, MASKED, CLAMPED)                        \
    PH2(13, c5, Q0, Q1, P0, P1, nq3.y, MASKED, CLAMPED)                        \
    PH2(14, c6, P0, P1, Q0, Q1, nq3.z, MASKED, CLAMPED)                        \
    PH2(15, c7, Q0, Q1, P0, P1, nq3.w, MASKED, CLAMPED)

#define PRIME(K)                                                               \
    c0 = skb2[(size_t)clampi((K) + 0) * 256];                                  \
    c1 = skb2[(size_t)clampi((K) + 1) * 256];                                  \
    c2 = skb2[(size_t)clampi((K) + 2) * 256];                                  \
    c3 = skb2[(size_t)clampi((K) + 3) * 256];                                  \
    c4 = skb2[(size_t)clampi((K) + 4) * 256];                                  \
    c5 = skb2[(size_t)clampi((K) + 5) * 256];                                  \
    c6 = skb2[(size_t)clampi((K) + 6) * 256];                                  \
    c7 = skb2[(size_t)clampi((K) + 7) * 256];

__global__ __launch_bounds__(256) void sdtw_dp(const float* __restrict__ skew,
                                               float* __restrict__ out) {
    const int b   = blockIdx.x;
    const int tid = threadIdx.x;
    const int w   = tid >> 6;
    const int lt  = tid & 63;
    // lane's rows: r0 = 128w + 2lt, r1 = r0+1 -> float2 at index 64w+lt
    const float2* skb2 = reinterpret_cast<const float2*>(
                             skew + (size_t)b * (NDIAG * TLEN)) + (64 * w + lt);

    __shared__ float4 bnd4[5][8];                // [consumer wave][quad slot]
    if (tid < 160) ((float*)bnd4)[tid] = BIGV;

    float P0 = BIGV, P1 = BIGV, Q0 = BIGV, Q1 = BIGV;
    float vBig  = BIGV;
    float bd_up = BIGV;
    float dgs   = (tid == 0) ? 0.0f : BIGV;      // R(0,0)=0 enters at kd=0 lane0 w0
    float4 bq = make_float4(BIGV, BIGV, BIGV, BIGV);

    __syncthreads();

    float2 c0, c1, c2, c3, c4, c5, c6, c7;
    PRIME(0)                                     // real for w=0; re-primed at warm-up

    for (int s = 0; s < 67; ++s) {
        const int sw  = s - 9 * w;               // wave-uniform
        const int kd0 = 16 * (s - w);
        const int q0  = (kd0 >> 2) & 7;
        const int vb0 = kd0 - (128 * w + 2 * lt);

        if (sw >= -1 && sw <= 39) {
            // hoisted boundary quads (written in segment s-1 -> race-free)
            float4 nq0 = bnd4[w][q0];
            float4 nq1 = bnd4[w][(q0 + 1) & 7];
            float4 nq2 = bnd4[w][(q0 + 2) & 7];
            float4 nq3 = bnd4[w][(q0 + 3) & 7];
            if (sw == -1) { PRIME(kd0) }         // warm-up: re-prime prefetch
            if (sw >= 8 && sw <= 31) { SEG_BODY(0, 0) }   // interior
            else                     { SEG_BODY(1, 1) }   // staircase/warm-up
        } else {
            if (lt == 63) {                      // junk: keep boundary cadence
                float4 bigq = make_float4(BIGV, BIGV, BIGV, BIGV);
                bnd4[w + 1][q0]           = bigq;
                bnd4[w + 1][(q0 + 1) & 7] = bigq;
                bnd4[w + 1][(q0 + 2) & 7] = bigq;
                bnd4[w + 1][(q0 + 3) & 7] = bigq;
            }
        }
        __syncthreads();
    }

    if (tid == 255) out[b] = Q1 * LN2;           // diag 1022 (even) -> Q, row 511
}

// ---------------------------------------------------------------- launcher
extern "C" void kernel_launch(void* const* d_in, const int* in_sizes, int n_in,
                              void* d_out, int out_size, void* d_ws, size_t ws_size,
                              hipStream_t stream) {
    const float* x = (const float*)d_in[0];
    const float* y = (const float*)d_in[1];
    float* outp = (float*)d_out;

    float* invnx = (float*)d_ws;                          //  16,384 floats
    float* invny = invnx + (size_t)BT * TLEN;             //  16,384 floats
    float* skew  = invny + (size_t)BT * TLEN;             //  16,760,832 floats

    sdtw_invnorm<<<dim3(BT * TLEN / 4, 2), dim3(256), 0, stream>>>(x, y, invnx, invny);
    sdtw_gemm_skew<<<dim3(4, 4, BT), dim3(256), 0, stream>>>(x, y, invnx, invny, skew);
    sdtw_dp<<<dim3(BT), dim3(256), 0, stream>>>(skew, outp);
}

// Round 10
// 161.146 us; speedup vs baseline: 1.0454x; 1.0454x over previous
//
#include <hip/hip_runtime.h>
#include <hip/hip_bf16.h>
#include <cstdint>

// Problem: B=32, T1=T2=512, D=128, gamma=1.0
// out[b] = softDTW( 1 - cos_sim(x[b], y[b]) )
//
// ws layout (floats):
//   invnx : 32*512            =     16,384
//   invny : 32*512            =     16,384
//   skew  : 32*1023*512       = 16,760,832   (cost/ln2 in anti-diagonal layout)

#define BT      32
#define TLEN    512
#define DF      128
#define NDIAG   1023          // kd = 0..1022  (kd = i-1 + j-1)
#define BIGV    1e30f
#define INV_LN2 1.44269504088896340f
#define LN2     0.69314718055994531f

// ------------------------------------------------------------- inverse norms
__global__ __launch_bounds__(256) void sdtw_invnorm(const float* __restrict__ x,
                                                    const float* __restrict__ y,
                                                    float* __restrict__ ox,
                                                    float* __restrict__ oy) {
    const float* in  = blockIdx.y ? y : x;
    float*       out = blockIdx.y ? oy : ox;
    int row = blockIdx.x * 4 + (threadIdx.x >> 6);
    int t   = threadIdx.x & 63;
    const float2* ip = reinterpret_cast<const float2*>(in + (size_t)row * DF);
    float2 v = ip[t];
    float s = v.x * v.x + v.y * v.y;
    #pragma unroll
    for (int o = 32; o; o >>= 1) s += __shfl_xor(s, o);
    if (t == 0) out[row] = 1.0f / fmaxf(sqrtf(s), 1e-12f);
}

// ------------------------------------------------- cosine-dist GEMM -> skew
#define KC   32
#define SPAD 132

__global__ __launch_bounds__(256) void sdtw_gemm_skew(const float* __restrict__ x,
                                                      const float* __restrict__ y,
                                                      const float* __restrict__ invnx,
                                                      const float* __restrict__ invny,
                                                      float* __restrict__ skew) {
    __shared__ float smem[16640];
    float* xs = smem;                        // [KC][SPAD] transposed: xs[k][row]
    float* ys = smem + KC * SPAD;

    const int b  = blockIdx.z;
    const int r0 = blockIdx.y * 128;
    const int c0 = blockIdx.x * 128;
    const int tid = threadIdx.x;
    const int tx = tid & 15, ty = tid >> 4;

    const float* xb = x + ((size_t)b * TLEN + r0) * DF;
    const float* yb = y + ((size_t)b * TLEN + c0) * DF;

    float acc[8][8];
    #pragma unroll
    for (int i = 0; i < 8; ++i)
        #pragma unroll
        for (int j = 0; j < 8; ++j) acc[i][j] = 0.0f;

    for (int kb = 0; kb < DF; kb += KC) {
        __syncthreads();
        #pragma unroll
        for (int i = 0; i < 4; ++i) {
            int g   = tid + i * 256;
            int row = g >> 3;
            int kq  = g & 7;
            float4 vx = *reinterpret_cast<const float4*>(xb + (size_t)row * DF + kb + kq * 4);
            float4 vy = *reinterpret_cast<const float4*>(yb + (size_t)row * DF + kb + kq * 4);
            xs[(kq * 4 + 0) * SPAD + row] = vx.x;
            xs[(kq * 4 + 1) * SPAD + row] = vx.y;
            xs[(kq * 4 + 2) * SPAD + row] = vx.z;
            xs[(kq * 4 + 3) * SPAD + row] = vx.w;
            ys[(kq * 4 + 0) * SPAD + row] = vy.x;
            ys[(kq * 4 + 1) * SPAD + row] = vy.y;
            ys[(kq * 4 + 2) * SPAD + row] = vy.z;
            ys[(kq * 4 + 3) * SPAD + row] = vy.w;
        }
        __syncthreads();
        #pragma unroll
        for (int k = 0; k < KC; ++k) {
            float ax[8], ay[8];
            *reinterpret_cast<float4*>(&ax[0]) = *reinterpret_cast<const float4*>(&xs[k * SPAD + ty * 8]);
            *reinterpret_cast<float4*>(&ax[4]) = *reinterpret_cast<const float4*>(&xs[k * SPAD + ty * 8 + 4]);
            *reinterpret_cast<float4*>(&ay[0]) = *reinterpret_cast<const float4*>(&ys[k * SPAD + tx * 8]);
            *reinterpret_cast<float4*>(&ay[4]) = *reinterpret_cast<const float4*>(&ys[k * SPAD + tx * 8 + 4]);
            #pragma unroll
            for (int i = 0; i < 8; ++i)
                #pragma unroll
                for (int j = 0; j < 8; ++j)
                    acc[i][j] = fmaf(ax[i], ay[j], acc[i][j]);
        }
    }

    // epilogue: (1 - dot*invnx*invny)/ln2 into LDS tile [128][130]
    float rn[8], cn[8];
    #pragma unroll
    for (int i = 0; i < 8; ++i) rn[i] = invnx[b * TLEN + r0 + ty * 8 + i];
    #pragma unroll
    for (int j = 0; j < 8; ++j) cn[j] = invny[b * TLEN + c0 + tx * 8 + j];

    __syncthreads();
    float* cs = smem;
    #pragma unroll
    for (int i = 0; i < 8; ++i)
        #pragma unroll
        for (int j = 0; j < 8; ++j)
            cs[(ty * 8 + i) * 130 + tx * 8 + j] =
                (1.0f - acc[i][j] * rn[i] * cn[j]) * INV_LN2;
    __syncthreads();

    float* sk = skew + (size_t)b * (NDIAG * TLEN);
    const int wv = tid >> 6, l = tid & 63;
    for (int dd = wv; dd < 255; dd += 4) {
        int lo = max(0, dd - 127), hi = min(127, dd);
        size_t base = (size_t)(r0 + c0 + dd) * TLEN + r0;
        for (int rb = lo; rb <= hi; rb += 64) {
            int rl = rb + l;
            if (rl <= hi) sk[base + rl] = cs[rl * 129 + dd];   // rl*130 + (dd-rl)
        }
    }
}

// ----------------------------------------------------------------- DTW DP
// 8 waves per batch (512 threads), lane owns row r = 64*chunk + lt.
// SIMD-AWARE CHUNK REMAP: wave ww -> chunk = ((ww&3)<<1)|(ww>>2), so the two
// waves sharing a SIMD (ww, ww+4 -> SIMD ww%4) own ADJACENT chunks 2k,2k+1
// whose active windows overlap 32/37 segments -> 2 co-active waves per SIMD
// fill each other's softmin-chain stalls (R6 had offset 20, overlap 17/37 ->
// effectively 1 active wave/SIMD, chain exposed).
// Chunk c processes diag kd at phase p = kd + 16c; one __syncthreads per
// 16-phase segment. Segment modes (wave-uniform): JUNK / PARTIAL(mask+clamp,
// warm-up sw==-1 re-primes prefetch & rebuilds bd_up/dgs) / INTERIOR.
// Per phase: 1 softmin; lane-0 patch via DPP wave_shr:1 with old=bd_up;
// dg carried in dgs (== patched up of previous phase). Boundary values flow
// as float4 quads through bnd4[chunk+1] (write) / bnd4[chunk] (read, hoisted
// to segment start; every quad was completed in segment s-1 -> race-free).
// 71 segments * 16 = 1136 phases; answer: diag 1022 (even -> Q) of chunk 7
// lane 63 (= wave 7 = tid 511 under the remap).

__device__ __forceinline__ int clampi(int v) {
    return v < 0 ? 0 : (v > NDIAG - 1 ? NDIAG - 1 : v);
}

__device__ __forceinline__ float dpp_shr1_old(float old, float x) {
    return __builtin_bit_cast(float,
        __builtin_amdgcn_update_dpp(__builtin_bit_cast(int, old),
                                    __builtin_bit_cast(int, x),
                                    0x138 /*wave_shr:1*/, 0xF, 0xF, false));
}

#define PH(s, CC, PN, PO, NQC, MASKED, CLAMPED)                                \
  {                                                                            \
    float up_ = dpp_shr1_old(bd_up, PN);     /* lane0 <- bd_up */              \
    float dg_ = dgs;                         /* patched up_ of prev phase */   \
    float m_   = fminf(fminf(dg_, PN), up_);                                   \
    float mid_ = __builtin_amdgcn_fmed3f(dg_, PN, up_);                        \
    float mx_  = fmaxf(fmaxf(dg_, PN), up_);                                   \
    float e_   = 1.0f + __builtin_amdgcn_exp2f(m_ - mid_)                      \
                      + __builtin_amdgcn_exp2f(m_ - mx_);                      \
    float v_   = CC + m_ - __builtin_amdgcn_logf(e_);                          \
    PO = (MASKED) ? (((unsigned)(vb0 + (s)) < 512u) ? v_ : vBig) : v_;         \
    if (((s) & 3) == 0) bq.x = PO;                                             \
    if (((s) & 3) == 1) bq.y = PO;                                             \
    if (((s) & 3) == 2) bq.z = PO;                                             \
    if (((s) & 3) == 3) { bq.w = PO;                                           \
      if (lt == 63) bnd4[c + 1][(q0 + ((s) >> 2)) & 7] = bq; }                 \
    bd_up = (NQC);                                                             \
    dgs = up_;                                                                 \
    { int kl_ = kd0 + (s) + 8; if (CLAMPED) kl_ = clampi(kl_);                 \
      CC = skb[(size_t)kl_ * TLEN]; }                                          \
  }

#define SEG_BODY(MASKED, CLAMPED)                                              \
    PH(0,  c0, P, Q, nq0.x, MASKED, CLAMPED) PH(1,  c1, Q, P, nq0.y, MASKED, CLAMPED) \
    PH(2,  c2, P, Q, nq0.z, MASKED, CLAMPED) PH(3,  c3, Q, P, nq0.w, MASKED, CLAMPED) \
    PH(4,  c4, P, Q, nq1.x, MASKED, CLAMPED) PH(5,  c5, Q, P, nq1.y, MASKED, CLAMPED) \
    PH(6,  c6, P, Q, nq1.z, MASKED, CLAMPED) PH(7,  c7, Q, P, nq1.w, MASKED, CLAMPED) \
    PH(8,  c0, P, Q, nq2.x, MASKED, CLAMPED) PH(9,  c1, Q, P, nq2.y, MASKED, CLAMPED) \
    PH(10, c2, P, Q, nq2.z, MASKED, CLAMPED) PH(11, c3, Q, P, nq2.w, MASKED, CLAMPED) \
    PH(12, c4, P, Q, nq3.x, MASKED, CLAMPED) PH(13, c5, Q, P, nq3.y, MASKED, CLAMPED) \
    PH(14, c6, P, Q, nq3.z, MASKED, CLAMPED) PH(15, c7, Q, P, nq3.w, MASKED, CLAMPED)

#define PRIME(K)                                                               \
    c0 = skb[(size_t)clampi((K) + 0) * TLEN];                                  \
    c1 = skb[(size_t)clampi((K) + 1) * TLEN];                                  \
    c2 = skb[(size_t)clampi((K) + 2) * TLEN];                                  \
    c3 = skb[(size_t)clampi((K) + 3) * TLEN];                                  \
    c4 = skb[(size_t)clampi((K) + 4) * TLEN];                                  \
    c5 = skb[(size_t)clampi((K) + 5) * TLEN];                                  \
    c6 = skb[(size_t)clampi((K) + 6) * TLEN];                                  \
    c7 = skb[(size_t)clampi((K) + 7) * TLEN];

__global__ __launch_bounds__(512) void sdtw_dp(const float* __restrict__ skew,
                                               float* __restrict__ out) {
    const int b   = blockIdx.x;
    const int tid = threadIdx.x;
    const int ww  = tid >> 6;                    // hardware wave id
    const int c   = ((ww & 3) << 1) | (ww >> 2); // chunk (SIMD-aware remap)
    const int lt  = tid & 63;
    const int row = 64 * c + lt;
    const float* skb = skew + (size_t)b * (NDIAG * TLEN) + row;

    __shared__ float4 bnd4[9][8];                // [consumer chunk][quad slot]
    if (tid < 288) ((float*)bnd4)[tid] = BIGV;

    float P = BIGV, Q = BIGV;
    float vBig  = BIGV;
    float bd_up = BIGV;
    // dgs: patched up_ of prev phase. First real use: chunk0 lane0 at kd=0
    // must see R(0,0)=0 (chunk0 == wave0, so tid==0).
    float dgs   = (tid == 0) ? 0.0f : BIGV;
    float4 bq = make_float4(BIGV, BIGV, BIGV, BIGV);

    __syncthreads();

    float c0, c1, c2, c3, c4, c5, c6, c7;
    PRIME(-16 * c)                               // real for chunk 0; re-primed at warm-up

    for (int s = 0; s < 71; ++s) {
        const int sw  = s - 5 * c;               // wave-uniform
        const int kd0 = 16 * (s - c);
        const int q0  = (kd0 >> 2) & 7;
        const int vb0 = kd0 - row;

        if (sw >= -1 && sw <= 35) {
            // hoisted boundary quads (all written in segment s-1 -> race-free)
            float4 nq0 = bnd4[c][q0];
            float4 nq1 = bnd4[c][(q0 + 1) & 7];
            float4 nq2 = bnd4[c][(q0 + 2) & 7];
            float4 nq3 = bnd4[c][(q0 + 3) & 7];
            if (sw == -1) { PRIME(kd0) }         // warm-up: re-prime prefetch
            if (sw >= 4 && sw <= 31) { SEG_BODY(0, 0) }   // interior
            else                     { SEG_BODY(1, 1) }   // staircase/warm-up
        } else {
            if (lt == 63) {                      // junk: keep boundary cadence
                float4 bigq = make_float4(BIGV, BIGV, BIGV, BIGV);
                bnd4[c + 1][q0]           = bigq;
                bnd4[c + 1][(q0 + 1) & 7] = bigq;
                bnd4[c + 1][(q0 + 2) & 7] = bigq;
                bnd4[c + 1][(q0 + 3) & 7] = bigq;
            }
        }
        __syncthreads();
    }

    if (tid == 511) out[b] = Q * LN2;            // chunk 7, row 511: R'(512,512)*ln2
}

// ---------------------------------------------------------------- launcher
extern "C" void kernel_launch(void* const* d_in, const int* in_sizes, int n_in,
                              void* d_out, int out_size, void* d_ws, size_t ws_size,
                              hipStream_t stream) {
    const float* x = (const float*)d_in[0];
    const float* y = (const float*)d_in[1];
    float* outp = (float*)d_out;

    float* invnx = (float*)d_ws;                          //  16,384 floats
    float* invny = invnx + (size_t)BT * TLEN;             //  16,384 floats
    float* skew  = invny + (size_t)BT * TLEN;             //  16,760,832 floats

    sdtw_invnorm<<<dim3(BT * TLEN / 4, 2), dim3(256), 0, stream>>>(x, y, invnx, invny);
    sdtw_gemm_skew<<<dim3(4, 4, BT), dim3(256), 0, stream>>>(x, y, invnx, invny, skew);
    sdtw_dp<<<dim3(BT), dim3(512), 0, stream>>>(skew, outp);
}